// Round 4
// baseline (495.160 us; speedup 1.0000x reference)
//
#include <hip/hip_runtime.h>

typedef _Float16 f16;
typedef _Float16 f16x8 __attribute__((ext_vector_type(8)));
typedef float f32x4 __attribute__((ext_vector_type(4)));

#define SEQ   196
#define EMB   768
#define NHEAD 12
#define HD    64
#define BATCH 256
#define TOK   (BATCH*SEQ)      /* 50176 */
#define QKVN  (3*EMB)          /* 2304  */
#define CLSK  (SEQ*EMB)        /* 150528 */

// ---------------- f32 -> f16 convert, 8 elems/thread ----------------
__global__ __launch_bounds__(256) void k_cvt8(const float* __restrict__ in,
                                              f16* __restrict__ out, int n8) {
  int i = blockIdx.x * 256 + threadIdx.x;
  if (i >= n8) return;
  const float4* p = (const float4*)in + (size_t)i * 2;
  float4 a = p[0], b = p[1];
  f16x8 o;
  o[0]=(f16)a.x; o[1]=(f16)a.y; o[2]=(f16)a.z; o[3]=(f16)a.w;
  o[4]=(f16)b.x; o[5]=(f16)b.y; o[6]=(f16)b.z; o[7]=(f16)b.w;
  *((f16x8*)out + i) = o;
}

// ------------- W[K][N] f32 -> WT[N][K] f16 (tiled transpose) -------------
__global__ __launch_bounds__(256) void k_transpose_cvt(const float* __restrict__ W,
                                                       f16* __restrict__ WT,
                                                       int K, int N) {
  __shared__ float tile[32][33];
  int n0 = blockIdx.x * 32, k0 = blockIdx.y * 32;
  int t = threadIdx.x, tx = t & 31, ty = t >> 5;
  #pragma unroll
  for (int i = 0; i < 4; ++i) {
    int r = ty + i * 8;
    tile[r][tx] = W[(size_t)(k0 + r) * N + n0 + tx];
  }
  __syncthreads();
  #pragma unroll
  for (int i = 0; i < 4; ++i) {
    int r = ty + i * 8;
    WT[(size_t)(n0 + r) * K + k0 + tx] = (f16)tile[tx][r];
  }
}

// ---------------- 256x256 8-phase GEMM: C = A * B^T + bias ----------------
// A[M][K], Bm[N][K] f16; BK=64, 8 waves (2Mx4N), 128x64 per wave.
// LDS 128 KiB: 2 dbuf x (256x64) for each of A,B. 16B-chunk XOR swizzle
// (source-side for global_load_lds, inverted on ds_read -> conflict-free).
// Schedule: phases 1-4 compute even tile (buf0) staging odd-tile rounds 1-3
// + next-even round 0; phases 5-8 mirror. Steady-state drain leaves one
// round (2 loads) in flight: vmcnt(2) at P4/P8. FINAL iteration: the t2/t3
// prefetches are not issued, so drain FULLY (vmcnt(0)) -- fixed-count
// vmcnt(2) there left round 3 of the last tile unlanded (round-3 race).
#define GLD16(gp, lp) __builtin_amdgcn_global_load_lds( \
    (const __attribute__((address_space(1))) void*)(gp), \
    (__attribute__((address_space(3))) void*)(lp), 16, 0, 0)

__global__ __launch_bounds__(512, 2) void k_gemm256(
    const f16* __restrict__ A, const f16* __restrict__ Bm,
    const float* __restrict__ bias, f16* __restrict__ C,
    int M, int N, int K) {
  __shared__ f16 As[2 * 256 * 64];   // 64 KiB
  __shared__ f16 Bs[2 * 256 * 64];   // 64 KiB
  const int t = threadIdx.x;
  const int l = t & 63;
  const int w = t >> 6;              // 0..7
  const int wm = w >> 2;             // 0..1 -> 128-row half
  const int wn = w & 3;              // 0..3 -> 64-col quarter
  const int bm = blockIdx.y, bn = blockIdx.x;
  const size_t rowA0 = (size_t)bm * 256, rowB0 = (size_t)bn * 256;
  const int KT = K >> 6;             // 12 (even)

  f32x4 acc[8][4] = {};
  f16x8 a[4][2], b0[2][2], b1[2][2];

  // stage one round (A+B, 2 loads): round r covers tile rows [64r, 64r+64)
  auto stage = [&](int kt, int round) {
    if (kt >= KT) return;
    int q = round * 512 + t;
    int r = q >> 3, c = q & 7;
    int cs = c ^ (r & 7);                       // pre-swizzled source chunk
    int buf = kt & 1;
    const f16* ga = A  + (rowA0 + r) * (size_t)K + kt * 64 + cs * 8;
    const f16* gb = Bm + (rowB0 + r) * (size_t)K + kt * 64 + cs * 8;
    GLD16(ga, As + buf * 16384 + q * 8);        // dest: wave-uniform + l*16B
    GLD16(gb, Bs + buf * 16384 + q * 8);
  };
  auto rdA = [&](int buf, int mi, int kk) -> f16x8 {
    int r = wm * 128 + mi * 16 + (l & 15);
    int k8 = kk * 4 + (l >> 4);
    return *(const f16x8*)((const char*)As + buf * 32768 + r * 128 + ((k8 ^ (r & 7)) << 4));
  };
  auto rdB = [&](int buf, int ni, int kk) -> f16x8 {
    int r = wn * 64 + ni * 16 + (l & 15);
    int k8 = kk * 4 + (l >> 4);
    return *(const f16x8*)((const char*)Bs + buf * 32768 + r * 128 + ((k8 ^ (r & 7)) << 4));
  };
  // drain so that the (possibly un-issued) newest round may stay in flight
  auto drain = [&](int kt) {
    if (kt < KT) { asm volatile("s_waitcnt vmcnt(2)" ::: "memory"); }
    else         { asm volatile("s_waitcnt vmcnt(0)" ::: "memory"); }
  };

#define PH_SYNC_PRE()  asm volatile("" ::: "memory"); __builtin_amdgcn_s_barrier(); \
                       __builtin_amdgcn_s_setprio(1)
#define PH_SYNC_POST() __builtin_amdgcn_s_setprio(0); asm volatile("" ::: "memory"); \
                       __builtin_amdgcn_s_barrier()

  // prologue: tile0 fully, tile1 round 0; wait tile0 landed (2 may fly)
  stage(0, 0); stage(0, 1); stage(0, 2); stage(0, 3); stage(1, 0);
  asm volatile("s_waitcnt vmcnt(2)" ::: "memory");
  __builtin_amdgcn_s_barrier();

  for (int it = 0; it < KT / 2; ++it) {
    const int t1 = 2 * it + 1, t2 = 2 * it + 2, t3 = 2 * it + 3;

    // ---- P1: read A-mh0 + B-h0 (buf0); stage t1 r1; mfma quad(mh0,nh0)
    #pragma unroll
    for (int i = 0; i < 4; ++i)
      #pragma unroll
      for (int kk = 0; kk < 2; ++kk) a[i][kk] = rdA(0, i, kk);
    #pragma unroll
    for (int ni = 0; ni < 2; ++ni)
      #pragma unroll
      for (int kk = 0; kk < 2; ++kk) b0[ni][kk] = rdB(0, ni, kk);
    stage(t1, 1);
    PH_SYNC_PRE();
    #pragma unroll
    for (int i = 0; i < 4; ++i)
      #pragma unroll
      for (int ni = 0; ni < 2; ++ni)
        #pragma unroll
        for (int kk = 0; kk < 2; ++kk)
          acc[i][ni] = __builtin_amdgcn_mfma_f32_16x16x32_f16(a[i][kk], b0[ni][kk], acc[i][ni], 0, 0, 0);
    PH_SYNC_POST();

    // ---- P2: read B-h1 (buf0); stage t1 r2; mfma quad(mh0,nh1)
    #pragma unroll
    for (int ni = 0; ni < 2; ++ni)
      #pragma unroll
      for (int kk = 0; kk < 2; ++kk) b1[ni][kk] = rdB(0, 2 + ni, kk);
    stage(t1, 2);
    PH_SYNC_PRE();
    #pragma unroll
    for (int i = 0; i < 4; ++i)
      #pragma unroll
      for (int ni = 0; ni < 2; ++ni)
        #pragma unroll
        for (int kk = 0; kk < 2; ++kk)
          acc[i][2 + ni] = __builtin_amdgcn_mfma_f32_16x16x32_f16(a[i][kk], b1[ni][kk], acc[i][2 + ni], 0, 0, 0);
    PH_SYNC_POST();

    // ---- P3: read A-mh1 (buf0, last buf0 read); stage t1 r3; mfma quad(mh1,nh1)
    #pragma unroll
    for (int i = 0; i < 4; ++i)
      #pragma unroll
      for (int kk = 0; kk < 2; ++kk) a[i][kk] = rdA(0, 4 + i, kk);
    stage(t1, 3);
    PH_SYNC_PRE();
    #pragma unroll
    for (int i = 0; i < 4; ++i)
      #pragma unroll
      for (int ni = 0; ni < 2; ++ni)
        #pragma unroll
        for (int kk = 0; kk < 2; ++kk)
          acc[4 + i][2 + ni] = __builtin_amdgcn_mfma_f32_16x16x32_f16(a[i][kk], b1[ni][kk], acc[4 + i][2 + ni], 0, 0, 0);
    PH_SYNC_POST();

    // ---- P4: stage t2 r0 (into buf0, reads done); drain; mfma quad(mh1,nh0)
    stage(t2, 0);
    drain(t2);
    PH_SYNC_PRE();
    #pragma unroll
    for (int i = 0; i < 4; ++i)
      #pragma unroll
      for (int ni = 0; ni < 2; ++ni)
        #pragma unroll
        for (int kk = 0; kk < 2; ++kk)
          acc[4 + i][ni] = __builtin_amdgcn_mfma_f32_16x16x32_f16(a[i][kk], b0[ni][kk], acc[4 + i][ni], 0, 0, 0);
    PH_SYNC_POST();

    // ---- P5: read A-mh0 + B-h0 (buf1); stage t2 r1; mfma quad(mh0,nh0)
    #pragma unroll
    for (int i = 0; i < 4; ++i)
      #pragma unroll
      for (int kk = 0; kk < 2; ++kk) a[i][kk] = rdA(1, i, kk);
    #pragma unroll
    for (int ni = 0; ni < 2; ++ni)
      #pragma unroll
      for (int kk = 0; kk < 2; ++kk) b0[ni][kk] = rdB(1, ni, kk);
    stage(t2, 1);
    PH_SYNC_PRE();
    #pragma unroll
    for (int i = 0; i < 4; ++i)
      #pragma unroll
      for (int ni = 0; ni < 2; ++ni)
        #pragma unroll
        for (int kk = 0; kk < 2; ++kk)
          acc[i][ni] = __builtin_amdgcn_mfma_f32_16x16x32_f16(a[i][kk], b0[ni][kk], acc[i][ni], 0, 0, 0);
    PH_SYNC_POST();

    // ---- P6: read B-h1 (buf1); stage t2 r2; mfma quad(mh0,nh1)
    #pragma unroll
    for (int ni = 0; ni < 2; ++ni)
      #pragma unroll
      for (int kk = 0; kk < 2; ++kk) b1[ni][kk] = rdB(1, 2 + ni, kk);
    stage(t2, 2);
    PH_SYNC_PRE();
    #pragma unroll
    for (int i = 0; i < 4; ++i)
      #pragma unroll
      for (int ni = 0; ni < 2; ++ni)
        #pragma unroll
        for (int kk = 0; kk < 2; ++kk)
          acc[i][2 + ni] = __builtin_amdgcn_mfma_f32_16x16x32_f16(a[i][kk], b1[ni][kk], acc[i][2 + ni], 0, 0, 0);
    PH_SYNC_POST();

    // ---- P7: read A-mh1 (buf1, last buf1 read); stage t2 r3; mfma quad(mh1,nh1)
    #pragma unroll
    for (int i = 0; i < 4; ++i)
      #pragma unroll
      for (int kk = 0; kk < 2; ++kk) a[i][kk] = rdA(1, 4 + i, kk);
    stage(t2, 3);
    PH_SYNC_PRE();
    #pragma unroll
    for (int i = 0; i < 4; ++i)
      #pragma unroll
      for (int ni = 0; ni < 2; ++ni)
        #pragma unroll
        for (int kk = 0; kk < 2; ++kk)
          acc[4 + i][2 + ni] = __builtin_amdgcn_mfma_f32_16x16x32_f16(a[i][kk], b1[ni][kk], acc[4 + i][2 + ni], 0, 0, 0);
    PH_SYNC_POST();

    // ---- P8: stage t3 r0 (into buf1, reads done); drain; mfma quad(mh1,nh0)
    stage(t3, 0);
    drain(t3);
    PH_SYNC_PRE();
    #pragma unroll
    for (int i = 0; i < 4; ++i)
      #pragma unroll
      for (int ni = 0; ni < 2; ++ni)
        #pragma unroll
        for (int kk = 0; kk < 2; ++kk)
          acc[4 + i][ni] = __builtin_amdgcn_mfma_f32_16x16x32_f16(a[i][kk], b0[ni][kk], acc[4 + i][ni], 0, 0, 0);
    PH_SYNC_POST();
  }

  // epilogue: C/D layout col = l&15, row = (l>>4)*4 + j
  #pragma unroll
  for (int ni = 0; ni < 4; ++ni) {
    int gcol = bn * 256 + wn * 64 + ni * 16 + (l & 15);
    float bs = bias[gcol];
    #pragma unroll
    for (int mi = 0; mi < 8; ++mi) {
      int grow0 = bm * 256 + wm * 128 + mi * 16 + (l >> 4) * 4;
      #pragma unroll
      for (int j = 0; j < 4; ++j)
        C[(size_t)(grow0 + j) * N + gcol] = (f16)(acc[mi][ni][j] + bs);
    }
  }
}

// ---------------- per-token 12x12 attention over heads ----------------
__global__ __launch_bounds__(64) void k_attn(const f16* __restrict__ qkv,
                                             f16* __restrict__ aout) {
  const int tok = blockIdx.x;
  const int l = threadIdx.x;
  __shared__ f16 row[QKVN];
  __shared__ float sc[144];
  __shared__ float aw[144];
  const uint2* src = (const uint2*)(qkv + (size_t)tok * QKVN);
  uint2* dst = (uint2*)row;
  #pragma unroll
  for (int i = 0; i < 9; ++i) dst[l + i * 64] = src[l + i * 64];
  __syncthreads();
  for (int p = l; p < 144; p += 64) {
    int i = p / 12, j = p - i * 12;
    const f16x8* q8 = (const f16x8*)(row + i * 192);
    const f16x8* k8 = (const f16x8*)(row + j * 192 + 64);
    float s = 0.f;
    #pragma unroll
    for (int d8 = 0; d8 < 8; ++d8) {
      f16x8 a = q8[d8], b = k8[d8];
      #pragma unroll
      for (int e = 0; e < 8; ++e) s += (float)a[e] * (float)b[e];
    }
    sc[p] = s * 0.125f;
  }
  __syncthreads();
  if (l < 12) {
    float m = -1e30f;
    #pragma unroll
    for (int j = 0; j < 12; ++j) m = fmaxf(m, sc[l * 12 + j]);
    float e[12], sum = 0.f;
    #pragma unroll
    for (int j = 0; j < 12; ++j) { e[j] = __expf(sc[l * 12 + j] - m); sum += e[j]; }
    float inv = 1.f / sum;
    #pragma unroll
    for (int j = 0; j < 12; ++j) aw[l * 12 + j] = e[j] * inv;
  }
  __syncthreads();
  float vv[12];
  #pragma unroll
  for (int j = 0; j < 12; ++j) vv[j] = (float)row[j * 192 + 128 + l];
  f16* op = aout + (size_t)tok * EMB;
  #pragma unroll
  for (int i = 0; i < 12; ++i) {
    float o = 0.f;
    #pragma unroll
    for (int j = 0; j < 12; ++j) o += aw[i * 12 + j] * vv[j];
    op[i * 64 + l] = (f16)o;
  }
}

// ---------------- classifier ----------------
__global__ __launch_bounds__(256) void k_cls(const f16* __restrict__ out2,
                                             const float* __restrict__ cls_w,
                                             const float* __restrict__ cls_b,
                                             float* __restrict__ logits) {
  const int b = blockIdx.x, t = threadIdx.x;
  const f16* r = out2 + (size_t)b * CLSK;
  float s0 = 0.f, s1 = 0.f, s2 = 0.f;
  for (int c8 = t; c8 < CLSK / 8; c8 += 256) {
    f16x8 v = *((const f16x8*)r + c8);
    float wv[24];
    const float4* wp = (const float4*)(cls_w + (size_t)c8 * 24);
    #pragma unroll
    for (int i = 0; i < 6; ++i) *(float4*)&wv[i * 4] = wp[i];
    #pragma unroll
    for (int e = 0; e < 8; ++e) {
      float f = (float)v[e];
      s0 += f * wv[e * 3 + 0];
      s1 += f * wv[e * 3 + 1];
      s2 += f * wv[e * 3 + 2];
    }
  }
  __shared__ float r0[256], r1[256], r2[256];
  r0[t] = s0; r1[t] = s1; r2[t] = s2;
  __syncthreads();
  for (int off = 128; off > 0; off >>= 1) {
    if (t < off) { r0[t] += r0[t + off]; r1[t] += r1[t + off]; r2[t] += r2[t + off]; }
    __syncthreads();
  }
  if (t == 0) {
    logits[b * 3 + 0] = r0[0] + cls_b[0];
    logits[b * 3 + 1] = r1[0] + cls_b[1];
    logits[b * 3 + 2] = r2[0] + cls_b[2];
  }
}

extern "C" void kernel_launch(void* const* d_in, const int* in_sizes, int n_in,
                              void* d_out, int out_size, void* d_ws, size_t ws_size,
                              hipStream_t stream) {
  (void)in_sizes; (void)n_in; (void)out_size;
  const float* x      = (const float*)d_in[0];
  const float* qkv_w  = (const float*)d_in[1];
  const float* qkv_b  = (const float*)d_in[2];
  const float* out_w  = (const float*)d_in[3];
  const float* out_b  = (const float*)d_in[4];
  const float* cls_w  = (const float*)d_in[5];
  const float* cls_b  = (const float*)d_in[6];
  float* logits = (float*)d_out;

  const size_t SZ_X16 = (size_t)TOK * EMB * 2;      // 77,070,336
  const size_t SZ_QKV = (size_t)TOK * QKVN * 2;     // 231,211,008
  const size_t SZ_QT  = (size_t)QKVN * EMB * 2;     // 3,538,944
  const size_t SZ_OT  = (size_t)EMB * EMB * 2;      // 1,179,648
  if (ws_size < SZ_X16 + SZ_QKV + SZ_QT + SZ_OT) return;

  char* ws = (char*)d_ws;
  f16* x16  = (f16*)ws;
  f16* qkvb = (f16*)(ws + SZ_X16);
  f16* qkvT = (f16*)(ws + SZ_X16 + SZ_QKV);
  f16* outT = (f16*)(ws + SZ_X16 + SZ_QKV + SZ_QT);
  f16* attno = x16;   // overlay: x16 dead after GEMM1
  f16* out2  = qkvb;  // overlay: qkv dead after attention

  k_cvt8<<<dim3(TOK * EMB / 8 / 256), dim3(256), 0, stream>>>(x, x16, TOK * EMB / 8);
  k_transpose_cvt<<<dim3(QKVN / 32, EMB / 32), dim3(256), 0, stream>>>(qkv_w, qkvT, EMB, QKVN);
  k_transpose_cvt<<<dim3(EMB / 32, EMB / 32), dim3(256), 0, stream>>>(out_w, outT, EMB, EMB);
  k_gemm256<<<dim3(QKVN / 256, TOK / 256), dim3(512), 0, stream>>>(x16, qkvT, qkv_b, qkvb, TOK, QKVN, EMB);
  k_attn<<<dim3(TOK), dim3(64), 0, stream>>>(qkvb, attno);
  k_gemm256<<<dim3(EMB / 256, TOK / 256), dim3(512), 0, stream>>>(attno, outT, out_b, out2, TOK, EMB, EMB);
  k_cls<<<dim3(BATCH), dim3(256), 0, stream>>>(out2, cls_w, cls_b, logits);
}

// Round 5
// 477.449 us; speedup vs baseline: 1.0371x; 1.0371x over previous
//
#include <hip/hip_runtime.h>

typedef _Float16 f16;
typedef _Float16 f16x8 __attribute__((ext_vector_type(8)));
typedef float f32x4 __attribute__((ext_vector_type(4)));

#define SEQ   196
#define EMB   768
#define NHEAD 12
#define HD    64
#define BATCH 256
#define TOK   (BATCH*SEQ)      /* 50176 */
#define QKVN  (3*EMB)          /* 2304  */
#define CLSK  (SEQ*EMB)        /* 150528 */

// ---------------- f32 -> f16 convert, 8 elems/thread ----------------
__global__ __launch_bounds__(256) void k_cvt8(const float* __restrict__ in,
                                              f16* __restrict__ out, int n8) {
  int i = blockIdx.x * 256 + threadIdx.x;
  if (i >= n8) return;
  const float4* p = (const float4*)in + (size_t)i * 2;
  float4 a = p[0], b = p[1];
  f16x8 o;
  o[0]=(f16)a.x; o[1]=(f16)a.y; o[2]=(f16)a.z; o[3]=(f16)a.w;
  o[4]=(f16)b.x; o[5]=(f16)b.y; o[6]=(f16)b.z; o[7]=(f16)b.w;
  *((f16x8*)out + i) = o;
}

// ------------- W[K][N] f32 -> WT[N][K] f16 (tiled transpose) -------------
__global__ __launch_bounds__(256) void k_transpose_cvt(const float* __restrict__ W,
                                                       f16* __restrict__ WT,
                                                       int K, int N) {
  __shared__ float tile[32][33];
  int n0 = blockIdx.x * 32, k0 = blockIdx.y * 32;
  int t = threadIdx.x, tx = t & 31, ty = t >> 5;
  #pragma unroll
  for (int i = 0; i < 4; ++i) {
    int r = ty + i * 8;
    tile[r][tx] = W[(size_t)(k0 + r) * N + n0 + tx];
  }
  __syncthreads();
  #pragma unroll
  for (int i = 0; i < 4; ++i) {
    int r = ty + i * 8;
    WT[(size_t)(n0 + r) * K + k0 + tx] = (f16)tile[tx][r];
  }
}

// ---------------- 256x256 8-phase GEMM: C = A * B^T + bias ----------------
// A[M][K], Bm[N][K] f16; BK=64, 8 waves (2Mx4N), 128x64 per wave.
// LDS 128 KiB: 2 dbuf x (256x64) for each of A,B. 16B-chunk XOR swizzle
// (source-side for global_load_lds, inverted on ds_read -> conflict-free).
//
// DEEP-PIPELINE STAGING (r5 restagger): per iteration compute tiles u (buf0,
// P1-P4) and u+1 (buf1, P5-P8). Stage tile u+2 in W2/W3/W4 and tile u+3 in
// W6/W7/W8 -- each stage lands one barrier AFTER its LDS region's last
// ds_read (WAR-safe): A-r0/r2 last read W1 -> stage W2; B last read W2 ->
// stage W3; A-r1/r3 last read W3 -> stage W4 (mirrored +4 for buf1).
// Drains vmcnt(8) at P4/P8 leave a full 8-load tile in flight and only
// force loads issued 4-6 phases earlier (HBM latency hidden). Tail: when
// the younger tile was not issued (kt>=KT), drain fully (vmcnt(0)).
#define GLD16(gp, lp) __builtin_amdgcn_global_load_lds( \
    (const __attribute__((address_space(1))) void*)(gp), \
    (__attribute__((address_space(3))) void*)(lp), 16, 0, 0)

__global__ __launch_bounds__(512, 2) void k_gemm256(
    const f16* __restrict__ A, const f16* __restrict__ Bm,
    const float* __restrict__ bias, f16* __restrict__ C,
    int M, int N, int K) {
  __shared__ f16 As[2 * 256 * 64];   // 64 KiB
  __shared__ f16 Bs[2 * 256 * 64];   // 64 KiB
  const int t = threadIdx.x;
  const int l = t & 63;
  const int w = t >> 6;              // 0..7
  const int wm = w >> 2;             // 0..1 -> 128-row half
  const int wn = w & 3;              // 0..3 -> 64-col quarter
  const int bm = blockIdx.y, bn = blockIdx.x;
  const size_t rowA0 = (size_t)bm * 256, rowB0 = (size_t)bn * 256;
  const int KT = K >> 6;             // 12 (even)

  f32x4 acc[8][4] = {};
  f16x8 a[4][2], b0[2][2], b1[2][2];

  // one 16B load per thread: round rd covers tile rows [64rd, 64rd+64)
  auto stageA = [&](int kt, int rd) {
    if (kt >= KT) return;
    int q = rd * 512 + t;
    int r = q >> 3, c = q & 7;
    int cs = c ^ (r & 7);                       // pre-swizzled source chunk
    GLD16(A + (rowA0 + r) * (size_t)K + kt * 64 + cs * 8,
          As + (kt & 1) * 16384 + q * 8);
  };
  auto stageB = [&](int kt, int rd) {
    if (kt >= KT) return;
    int q = rd * 512 + t;
    int r = q >> 3, c = q & 7;
    int cs = c ^ (r & 7);
    GLD16(Bm + (rowB0 + r) * (size_t)K + kt * 64 + cs * 8,
          Bs + (kt & 1) * 16384 + q * 8);
  };
  auto rdA = [&](int buf, int mi, int kk) -> f16x8 {
    int r = wm * 128 + mi * 16 + (l & 15);
    int k8 = kk * 4 + (l >> 4);
    return *(const f16x8*)((const char*)As + buf * 32768 + r * 128 + ((k8 ^ (r & 7)) << 4));
  };
  auto rdB = [&](int buf, int ni, int kk) -> f16x8 {
    int r = wn * 64 + ni * 16 + (l & 15);
    int k8 = kk * 4 + (l >> 4);
    return *(const f16x8*)((const char*)Bs + buf * 32768 + r * 128 + ((k8 ^ (r & 7)) << 4));
  };
  // drain: younger tile issued -> keep its 8 loads flying; else full drain
  auto drain = [&](int kt) {
    if (kt < KT) { asm volatile("s_waitcnt vmcnt(8)" ::: "memory"); }
    else         { asm volatile("s_waitcnt vmcnt(0)" ::: "memory"); }
  };

#define PH_SYNC_PRE()  asm volatile("" ::: "memory"); __builtin_amdgcn_s_barrier(); \
                       __builtin_amdgcn_s_setprio(1)
#define PH_SYNC_POST() __builtin_amdgcn_s_setprio(0); asm volatile("" ::: "memory"); \
                       __builtin_amdgcn_s_barrier()

  // prologue: tiles 0 and 1 fully issued (16 loads); tile0 forced landed
  #pragma unroll
  for (int rd = 0; rd < 4; ++rd) { stageA(0, rd); stageB(0, rd); }
  #pragma unroll
  for (int rd = 0; rd < 4; ++rd) { stageA(1, rd); stageB(1, rd); }
  asm volatile("s_waitcnt vmcnt(8)" ::: "memory");
  __builtin_amdgcn_s_barrier();

  for (int it = 0; it < KT / 2; ++it) {
    const int t2 = 2 * it + 2, t3 = 2 * it + 3;

    // ---- P1 (W1): read a=A-mh0, b0=B-h0 (buf0); mfma quad(mh0,nh0)
    #pragma unroll
    for (int i = 0; i < 4; ++i)
      #pragma unroll
      for (int kk = 0; kk < 2; ++kk) a[i][kk] = rdA(0, i, kk);
    #pragma unroll
    for (int ni = 0; ni < 2; ++ni)
      #pragma unroll
      for (int kk = 0; kk < 2; ++kk) b0[ni][kk] = rdB(0, ni, kk);
    PH_SYNC_PRE();
    #pragma unroll
    for (int i = 0; i < 4; ++i)
      #pragma unroll
      for (int ni = 0; ni < 2; ++ni)
        #pragma unroll
        for (int kk = 0; kk < 2; ++kk)
          acc[i][ni] = __builtin_amdgcn_mfma_f32_16x16x32_f16(a[i][kk], b0[ni][kk], acc[i][ni], 0, 0, 0);
    PH_SYNC_POST();

    // ---- P2 (W2): read b1=B-h1 (buf0); stage A(t2, r0/r2); mfma quad(mh0,nh1)
    #pragma unroll
    for (int ni = 0; ni < 2; ++ni)
      #pragma unroll
      for (int kk = 0; kk < 2; ++kk) b1[ni][kk] = rdB(0, 2 + ni, kk);
    stageA(t2, 0); stageA(t2, 2);
    PH_SYNC_PRE();
    #pragma unroll
    for (int i = 0; i < 4; ++i)
      #pragma unroll
      for (int ni = 0; ni < 2; ++ni)
        #pragma unroll
        for (int kk = 0; kk < 2; ++kk)
          acc[i][2 + ni] = __builtin_amdgcn_mfma_f32_16x16x32_f16(a[i][kk], b1[ni][kk], acc[i][2 + ni], 0, 0, 0);
    PH_SYNC_POST();

    // ---- P3 (W3): read a=A-mh1 (buf0); stage B(t2, all); mfma quad(mh1,nh1)
    #pragma unroll
    for (int i = 0; i < 4; ++i)
      #pragma unroll
      for (int kk = 0; kk < 2; ++kk) a[i][kk] = rdA(0, 4 + i, kk);
    stageB(t2, 0); stageB(t2, 1); stageB(t2, 2); stageB(t2, 3);
    PH_SYNC_PRE();
    #pragma unroll
    for (int i = 0; i < 4; ++i)
      #pragma unroll
      for (int ni = 0; ni < 2; ++ni)
        #pragma unroll
        for (int kk = 0; kk < 2; ++kk)
          acc[4 + i][2 + ni] = __builtin_amdgcn_mfma_f32_16x16x32_f16(a[i][kk], b1[ni][kk], acc[4 + i][2 + ni], 0, 0, 0);
    PH_SYNC_POST();

    // ---- P4 (W4): stage A(t2, r1/r3); drain(force tile u+1 landed); mfma quad(mh1,nh0)
    stageA(t2, 1); stageA(t2, 3);
    drain(t2);
    PH_SYNC_PRE();
    #pragma unroll
    for (int i = 0; i < 4; ++i)
      #pragma unroll
      for (int ni = 0; ni < 2; ++ni)
        #pragma unroll
        for (int kk = 0; kk < 2; ++kk)
          acc[4 + i][ni] = __builtin_amdgcn_mfma_f32_16x16x32_f16(a[i][kk], b0[ni][kk], acc[4 + i][ni], 0, 0, 0);
    PH_SYNC_POST();

    // ---- P5 (W5): read a, b0 (buf1); mfma quad(mh0,nh0)
    #pragma unroll
    for (int i = 0; i < 4; ++i)
      #pragma unroll
      for (int kk = 0; kk < 2; ++kk) a[i][kk] = rdA(1, i, kk);
    #pragma unroll
    for (int ni = 0; ni < 2; ++ni)
      #pragma unroll
      for (int kk = 0; kk < 2; ++kk) b0[ni][kk] = rdB(1, ni, kk);
    PH_SYNC_PRE();
    #pragma unroll
    for (int i = 0; i < 4; ++i)
      #pragma unroll
      for (int ni = 0; ni < 2; ++ni)
        #pragma unroll
        for (int kk = 0; kk < 2; ++kk)
          acc[i][ni] = __builtin_amdgcn_mfma_f32_16x16x32_f16(a[i][kk], b0[ni][kk], acc[i][ni], 0, 0, 0);
    PH_SYNC_POST();

    // ---- P6 (W6): read b1 (buf1); stage A(t3, r0/r2); mfma quad(mh0,nh1)
    #pragma unroll
    for (int ni = 0; ni < 2; ++ni)
      #pragma unroll
      for (int kk = 0; kk < 2; ++kk) b1[ni][kk] = rdB(1, 2 + ni, kk);
    stageA(t3, 0); stageA(t3, 2);
    PH_SYNC_PRE();
    #pragma unroll
    for (int i = 0; i < 4; ++i)
      #pragma unroll
      for (int ni = 0; ni < 2; ++ni)
        #pragma unroll
        for (int kk = 0; kk < 2; ++kk)
          acc[i][2 + ni] = __builtin_amdgcn_mfma_f32_16x16x32_f16(a[i][kk], b1[ni][kk], acc[i][2 + ni], 0, 0, 0);
    PH_SYNC_POST();

    // ---- P7 (W7): read a=A-mh1 (buf1); stage B(t3, all); mfma quad(mh1,nh1)
    #pragma unroll
    for (int i = 0; i < 4; ++i)
      #pragma unroll
      for (int kk = 0; kk < 2; ++kk) a[i][kk] = rdA(1, 4 + i, kk);
    stageB(t3, 0); stageB(t3, 1); stageB(t3, 2); stageB(t3, 3);
    PH_SYNC_PRE();
    #pragma unroll
    for (int i = 0; i < 4; ++i)
      #pragma unroll
      for (int ni = 0; ni < 2; ++ni)
        #pragma unroll
        for (int kk = 0; kk < 2; ++kk)
          acc[4 + i][2 + ni] = __builtin_amdgcn_mfma_f32_16x16x32_f16(a[i][kk], b1[ni][kk], acc[4 + i][2 + ni], 0, 0, 0);
    PH_SYNC_POST();

    // ---- P8 (W8): stage A(t3, r1/r3); drain(force tile u+2 landed); mfma quad(mh1,nh0)
    stageA(t3, 1); stageA(t3, 3);
    drain(t3);
    PH_SYNC_PRE();
    #pragma unroll
    for (int i = 0; i < 4; ++i)
      #pragma unroll
      for (int ni = 0; ni < 2; ++ni)
        #pragma unroll
        for (int kk = 0; kk < 2; ++kk)
          acc[4 + i][ni] = __builtin_amdgcn_mfma_f32_16x16x32_f16(a[i][kk], b0[ni][kk], acc[4 + i][ni], 0, 0, 0);
    PH_SYNC_POST();
  }

  // epilogue: C/D layout col = l&15, row = (l>>4)*4 + j
  #pragma unroll
  for (int ni = 0; ni < 4; ++ni) {
    int gcol = bn * 256 + wn * 64 + ni * 16 + (l & 15);
    float bs = bias[gcol];
    #pragma unroll
    for (int mi = 0; mi < 8; ++mi) {
      int grow0 = bm * 256 + wm * 128 + mi * 16 + (l >> 4) * 4;
      #pragma unroll
      for (int j = 0; j < 4; ++j)
        C[(size_t)(grow0 + j) * N + gcol] = (f16)(acc[mi][ni][j] + bs);
    }
  }
}

// ---------------- per-token 12x12 attention over heads ----------------
__global__ __launch_bounds__(64) void k_attn(const f16* __restrict__ qkv,
                                             f16* __restrict__ aout) {
  const int tok = blockIdx.x;
  const int l = threadIdx.x;
  __shared__ f16 row[QKVN];
  __shared__ float sc[144];
  __shared__ float aw[144];
  const uint2* src = (const uint2*)(qkv + (size_t)tok * QKVN);
  uint2* dst = (uint2*)row;
  #pragma unroll
  for (int i = 0; i < 9; ++i) dst[l + i * 64] = src[l + i * 64];
  __syncthreads();
  for (int p = l; p < 144; p += 64) {
    int i = p / 12, j = p - i * 12;
    const f16x8* q8 = (const f16x8*)(row + i * 192);
    const f16x8* k8 = (const f16x8*)(row + j * 192 + 64);
    float s = 0.f;
    #pragma unroll
    for (int d8 = 0; d8 < 8; ++d8) {
      f16x8 a = q8[d8], b = k8[d8];
      #pragma unroll
      for (int e = 0; e < 8; ++e) s += (float)a[e] * (float)b[e];
    }
    sc[p] = s * 0.125f;
  }
  __syncthreads();
  if (l < 12) {
    float m = -1e30f;
    #pragma unroll
    for (int j = 0; j < 12; ++j) m = fmaxf(m, sc[l * 12 + j]);
    float e[12], sum = 0.f;
    #pragma unroll
    for (int j = 0; j < 12; ++j) { e[j] = __expf(sc[l * 12 + j] - m); sum += e[j]; }
    float inv = 1.f / sum;
    #pragma unroll
    for (int j = 0; j < 12; ++j) aw[l * 12 + j] = e[j] * inv;
  }
  __syncthreads();
  float vv[12];
  #pragma unroll
  for (int j = 0; j < 12; ++j) vv[j] = (float)row[j * 192 + 128 + l];
  f16* op = aout + (size_t)tok * EMB;
  #pragma unroll
  for (int i = 0; i < 12; ++i) {
    float o = 0.f;
    #pragma unroll
    for (int j = 0; j < 12; ++j) o += aw[i * 12 + j] * vv[j];
    op[i * 64 + l] = (f16)o;
  }
}

// ---------------- classifier ----------------
__global__ __launch_bounds__(256) void k_cls(const f16* __restrict__ out2,
                                             const float* __restrict__ cls_w,
                                             const float* __restrict__ cls_b,
                                             float* __restrict__ logits) {
  const int b = blockIdx.x, t = threadIdx.x;
  const f16* r = out2 + (size_t)b * CLSK;
  float s0 = 0.f, s1 = 0.f, s2 = 0.f;
  for (int c8 = t; c8 < CLSK / 8; c8 += 256) {
    f16x8 v = *((const f16x8*)r + c8);
    float wv[24];
    const float4* wp = (const float4*)(cls_w + (size_t)c8 * 24);
    #pragma unroll
    for (int i = 0; i < 6; ++i) *(float4*)&wv[i * 4] = wp[i];
    #pragma unroll
    for (int e = 0; e < 8; ++e) {
      float f = (float)v[e];
      s0 += f * wv[e * 3 + 0];
      s1 += f * wv[e * 3 + 1];
      s2 += f * wv[e * 3 + 2];
    }
  }
  __shared__ float r0[256], r1[256], r2[256];
  r0[t] = s0; r1[t] = s1; r2[t] = s2;
  __syncthreads();
  for (int off = 128; off > 0; off >>= 1) {
    if (t < off) { r0[t] += r0[t + off]; r1[t] += r1[t + off]; r2[t] += r2[t + off]; }
    __syncthreads();
  }
  if (t == 0) {
    logits[b * 3 + 0] = r0[0] + cls_b[0];
    logits[b * 3 + 1] = r1[0] + cls_b[1];
    logits[b * 3 + 2] = r2[0] + cls_b[2];
  }
}

extern "C" void kernel_launch(void* const* d_in, const int* in_sizes, int n_in,
                              void* d_out, int out_size, void* d_ws, size_t ws_size,
                              hipStream_t stream) {
  (void)in_sizes; (void)n_in; (void)out_size;
  const float* x      = (const float*)d_in[0];
  const float* qkv_w  = (const float*)d_in[1];
  const float* qkv_b  = (const float*)d_in[2];
  const float* out_w  = (const float*)d_in[3];
  const float* out_b  = (const float*)d_in[4];
  const float* cls_w  = (const float*)d_in[5];
  const float* cls_b  = (const float*)d_in[6];
  float* logits = (float*)d_out;

  const size_t SZ_X16 = (size_t)TOK * EMB * 2;      // 77,070,336
  const size_t SZ_QKV = (size_t)TOK * QKVN * 2;     // 231,211,008
  const size_t SZ_QT  = (size_t)QKVN * EMB * 2;     // 3,538,944
  const size_t SZ_OT  = (size_t)EMB * EMB * 2;      // 1,179,648
  if (ws_size < SZ_X16 + SZ_QKV + SZ_QT + SZ_OT) return;

  char* ws = (char*)d_ws;
  f16* x16  = (f16*)ws;
  f16* qkvb = (f16*)(ws + SZ_X16);
  f16* qkvT = (f16*)(ws + SZ_X16 + SZ_QKV);
  f16* outT = (f16*)(ws + SZ_X16 + SZ_QKV + SZ_QT);
  f16* attno = x16;   // overlay: x16 dead after GEMM1
  f16* out2  = qkvb;  // overlay: qkv dead after attention

  k_cvt8<<<dim3(TOK * EMB / 8 / 256), dim3(256), 0, stream>>>(x, x16, TOK * EMB / 8);
  k_transpose_cvt<<<dim3(QKVN / 32, EMB / 32), dim3(256), 0, stream>>>(qkv_w, qkvT, EMB, QKVN);
  k_transpose_cvt<<<dim3(EMB / 32, EMB / 32), dim3(256), 0, stream>>>(out_w, outT, EMB, EMB);
  k_gemm256<<<dim3(QKVN / 256, TOK / 256), dim3(512), 0, stream>>>(x16, qkvT, qkv_b, qkvb, TOK, QKVN, EMB);
  k_attn<<<dim3(TOK), dim3(64), 0, stream>>>(qkvb, attno);
  k_gemm256<<<dim3(EMB / 256, TOK / 256), dim3(512), 0, stream>>>(attno, outT, out_b, out2, TOK, EMB, EMB);
  k_cls<<<dim3(BATCH), dim3(256), 0, stream>>>(out2, cls_w, cls_b, logits);
}

// Round 6
// 462.368 us; speedup vs baseline: 1.0709x; 1.0326x over previous
//
#include <hip/hip_runtime.h>

typedef _Float16 f16;
typedef _Float16 f16x8 __attribute__((ext_vector_type(8)));
typedef float f32x4 __attribute__((ext_vector_type(4)));

#define SEQ   196
#define EMB   768
#define NHEAD 12
#define HD    64
#define BATCH 256
#define TOK   (BATCH*SEQ)      /* 50176 */
#define QKVN  (3*EMB)          /* 2304  */
#define CLSK  (SEQ*EMB)        /* 150528 */

// ---------------- f32 -> f16 convert, 8 elems/thread ----------------
__global__ __launch_bounds__(256) void k_cvt8(const float* __restrict__ in,
                                              f16* __restrict__ out, int n8) {
  int i = blockIdx.x * 256 + threadIdx.x;
  if (i >= n8) return;
  const float4* p = (const float4*)in + (size_t)i * 2;
  float4 a = p[0], b = p[1];
  f16x8 o;
  o[0]=(f16)a.x; o[1]=(f16)a.y; o[2]=(f16)a.z; o[3]=(f16)a.w;
  o[4]=(f16)b.x; o[5]=(f16)b.y; o[6]=(f16)b.z; o[7]=(f16)b.w;
  *((f16x8*)out + i) = o;
}

// ------------- W[K][N] f32 -> WT[N][K] f16 (tiled transpose) -------------
__global__ __launch_bounds__(256) void k_transpose_cvt(const float* __restrict__ W,
                                                       f16* __restrict__ WT,
                                                       int K, int N) {
  __shared__ float tile[32][33];
  int n0 = blockIdx.x * 32, k0 = blockIdx.y * 32;
  int t = threadIdx.x, tx = t & 31, ty = t >> 5;
  #pragma unroll
  for (int i = 0; i < 4; ++i) {
    int r = ty + i * 8;
    tile[r][tx] = W[(size_t)(k0 + r) * N + n0 + tx];
  }
  __syncthreads();
  #pragma unroll
  for (int i = 0; i < 4; ++i) {
    int r = ty + i * 8;
    WT[(size_t)(n0 + r) * K + k0 + tx] = (f16)tile[tx][r];
  }
}

// ---------------- GEMM: C[M][N] = A[M][K] * B^T[N][K] + bias, f16 in, f16 out
// r2 128x128/BK=64 structure (known 840 TF) + m204 bijective XCD-chunk
// swizzle: 1D grid, XCD x owns a CONTIGUOUS run of tiles (bn fastest within
// bm) so all N/128 blocks sharing an A-panel land on one XCD -> A-panel
// fetched ~once per XCD's L2 instead of ~5x from HBM.
__global__ __launch_bounds__(256) void k_gemm_bias(
    const f16* __restrict__ A, const f16* __restrict__ Bm,
    const float* __restrict__ bias, f16* __restrict__ C,
    int M, int N, int K) {
  __shared__ f16 As[128 * 64];
  __shared__ f16 Bs[128 * 64];
  const int t = threadIdx.x;
  const int l = t & 63;
  const int w = t >> 6;
  const int wr = w >> 1, wc = w & 1;

  // XCD swizzle (nwg % 8 == 0 for both grids here; formula general anyway)
  const int nwg = gridDim.x;
  const int orig = blockIdx.x;
  const int q = nwg >> 3, r8 = nwg & 7;
  const int xcd = orig & 7, seq = orig >> 3;
  const int base = xcd < r8 ? xcd * (q + 1) : r8 * (q + 1) + (xcd - r8) * q;
  const int wg = base + seq;
  const int NB = N >> 7;
  const int bm = wg / NB, bn = wg - bm * NB;

  const size_t rowA0 = (size_t)bm * 128, rowB0 = (size_t)bn * 128;

  f32x4 acc[4][4] = {};

  for (int k0 = 0; k0 < K; k0 += 64) {
    if (k0) __syncthreads();
    // stage A,B tiles: 1024 16B chunks each, 4 per thread
    #pragma unroll
    for (int i = 0; i < 4; ++i) {
      int qq = i * 256 + t;
      int rr = qq >> 3, c = qq & 7;
      int cs = c ^ (rr & 7);                     // pre-swizzled source chunk
      const f16* ga = A  + (rowA0 + rr) * K + k0 + cs * 8;
      const f16* gb = Bm + (rowB0 + rr) * K + k0 + cs * 8;
      f16* la = As + (size_t)(i * 256 + w * 64) * 8;  // wave-uniform base
      f16* lb = Bs + (size_t)(i * 256 + w * 64) * 8;
      __builtin_amdgcn_global_load_lds((const __attribute__((address_space(1))) void*)ga,
                                       (__attribute__((address_space(3))) void*)la, 16, 0, 0);
      __builtin_amdgcn_global_load_lds((const __attribute__((address_space(1))) void*)gb,
                                       (__attribute__((address_space(3))) void*)lb, 16, 0, 0);
    }
    __syncthreads();
    #pragma unroll
    for (int ks = 0; ks < 2; ++ks) {
      f16x8 av[4], bv[4];
      const int k8 = ks * 4 + (l >> 4);
      #pragma unroll
      for (int m = 0; m < 4; ++m) {
        int rr = wr * 64 + m * 16 + (l & 15);
        av[m] = *(const f16x8*)((const char*)As + rr * 128 + ((k8 ^ (rr & 7)) << 4));
      }
      #pragma unroll
      for (int n = 0; n < 4; ++n) {
        int rr = wc * 64 + n * 16 + (l & 15);
        bv[n] = *(const f16x8*)((const char*)Bs + rr * 128 + ((k8 ^ (rr & 7)) << 4));
      }
      #pragma unroll
      for (int m = 0; m < 4; ++m)
        #pragma unroll
        for (int n = 0; n < 4; ++n)
          acc[m][n] = __builtin_amdgcn_mfma_f32_16x16x32_f16(av[m], bv[n], acc[m][n], 0, 0, 0);
    }
  }
  // epilogue: C/D layout col = l&15, row = (l>>4)*4 + j  (guide m89/m91)
  #pragma unroll
  for (int n = 0; n < 4; ++n) {
    int gcol = bn * 128 + wc * 64 + n * 16 + (l & 15);
    float bs = bias[gcol];
    #pragma unroll
    for (int m = 0; m < 4; ++m) {
      int grow0 = bm * 128 + wr * 64 + m * 16 + (l >> 4) * 4;
      #pragma unroll
      for (int j = 0; j < 4; ++j)
        C[(size_t)(grow0 + j) * N + gcol] = (f16)(acc[m][n][j] + bs);
    }
  }
}

// ---------------- per-token 12x12 attention over heads ----------------
// qkv row layout: head h -> [h*192 .. h*192+63]=q, +64..127=k, +128..191=v
__global__ __launch_bounds__(64) void k_attn(const f16* __restrict__ qkv,
                                             f16* __restrict__ aout) {
  const int tok = blockIdx.x;
  const int l = threadIdx.x;
  __shared__ f16 row[QKVN];
  __shared__ float sc[144];
  __shared__ float aw[144];
  const uint2* src = (const uint2*)(qkv + (size_t)tok * QKVN);
  uint2* dst = (uint2*)row;
  #pragma unroll
  for (int i = 0; i < 9; ++i) dst[l + i * 64] = src[l + i * 64];
  __syncthreads();
  for (int p = l; p < 144; p += 64) {
    int i = p / 12, j = p - i * 12;
    const f16x8* q8 = (const f16x8*)(row + i * 192);
    const f16x8* k8 = (const f16x8*)(row + j * 192 + 64);
    float s = 0.f;
    #pragma unroll
    for (int d8 = 0; d8 < 8; ++d8) {
      f16x8 a = q8[d8], b = k8[d8];
      #pragma unroll
      for (int e = 0; e < 8; ++e) s += (float)a[e] * (float)b[e];
    }
    sc[p] = s * 0.125f;
  }
  __syncthreads();
  if (l < 12) {
    float m = -1e30f;
    #pragma unroll
    for (int j = 0; j < 12; ++j) m = fmaxf(m, sc[l * 12 + j]);
    float e[12], sum = 0.f;
    #pragma unroll
    for (int j = 0; j < 12; ++j) { e[j] = __expf(sc[l * 12 + j] - m); sum += e[j]; }
    float inv = 1.f / sum;
    #pragma unroll
    for (int j = 0; j < 12; ++j) aw[l * 12 + j] = e[j] * inv;
  }
  __syncthreads();
  float vv[12];
  #pragma unroll
  for (int j = 0; j < 12; ++j) vv[j] = (float)row[j * 192 + 128 + l];
  f16* op = aout + (size_t)tok * EMB;
  #pragma unroll
  for (int i = 0; i < 12; ++i) {
    float o = 0.f;
    #pragma unroll
    for (int j = 0; j < 12; ++j) o += aw[i * 12 + j] * vv[j];
    op[i * 64 + l] = (f16)o;
  }
}

// ---------------- classifier: per-batch 150528-dim dot with 3 cols ----------------
__global__ __launch_bounds__(256) void k_cls(const f16* __restrict__ out2,
                                             const float* __restrict__ cls_w,
                                             const float* __restrict__ cls_b,
                                             float* __restrict__ logits) {
  const int b = blockIdx.x, t = threadIdx.x;
  const f16* r = out2 + (size_t)b * CLSK;
  float s0 = 0.f, s1 = 0.f, s2 = 0.f;
  for (int c8 = t; c8 < CLSK / 8; c8 += 256) {
    f16x8 v = *((const f16x8*)r + c8);
    float wv[24];
    const float4* wp = (const float4*)(cls_w + (size_t)c8 * 24);
    #pragma unroll
    for (int i = 0; i < 6; ++i) *(float4*)&wv[i * 4] = wp[i];
    #pragma unroll
    for (int e = 0; e < 8; ++e) {
      float f = (float)v[e];
      s0 += f * wv[e * 3 + 0];
      s1 += f * wv[e * 3 + 1];
      s2 += f * wv[e * 3 + 2];
    }
  }
  __shared__ float r0[256], r1[256], r2[256];
  r0[t] = s0; r1[t] = s1; r2[t] = s2;
  __syncthreads();
  for (int off = 128; off > 0; off >>= 1) {
    if (t < off) { r0[t] += r0[t + off]; r1[t] += r1[t + off]; r2[t] += r2[t + off]; }
    __syncthreads();
  }
  if (t == 0) {
    logits[b * 3 + 0] = r0[0] + cls_b[0];
    logits[b * 3 + 1] = r1[0] + cls_b[1];
    logits[b * 3 + 2] = r2[0] + cls_b[2];
  }
}

extern "C" void kernel_launch(void* const* d_in, const int* in_sizes, int n_in,
                              void* d_out, int out_size, void* d_ws, size_t ws_size,
                              hipStream_t stream) {
  (void)in_sizes; (void)n_in; (void)out_size;
  const float* x      = (const float*)d_in[0];
  const float* qkv_w  = (const float*)d_in[1];
  const float* qkv_b  = (const float*)d_in[2];
  const float* out_w  = (const float*)d_in[3];
  const float* out_b  = (const float*)d_in[4];
  const float* cls_w  = (const float*)d_in[5];
  const float* cls_b  = (const float*)d_in[6];
  float* logits = (float*)d_out;

  const size_t SZ_X16 = (size_t)TOK * EMB * 2;      // 77,070,336
  const size_t SZ_QKV = (size_t)TOK * QKVN * 2;     // 231,211,008
  const size_t SZ_QT  = (size_t)QKVN * EMB * 2;     // 3,538,944
  const size_t SZ_OT  = (size_t)EMB * EMB * 2;      // 1,179,648
  if (ws_size < SZ_X16 + SZ_QKV + SZ_QT + SZ_OT) return;

  char* ws = (char*)d_ws;
  f16* x16  = (f16*)ws;
  f16* qkvb = (f16*)(ws + SZ_X16);
  f16* qkvT = (f16*)(ws + SZ_X16 + SZ_QKV);
  f16* outT = (f16*)(ws + SZ_X16 + SZ_QKV + SZ_QT);
  f16* attno = x16;   // overlay: x16 dead after GEMM1
  f16* out2  = qkvb;  // overlay: qkv dead after attention

  k_cvt8<<<dim3(TOK * EMB / 8 / 256), dim3(256), 0, stream>>>(x, x16, TOK * EMB / 8);
  k_transpose_cvt<<<dim3(QKVN / 32, EMB / 32), dim3(256), 0, stream>>>(qkv_w, qkvT, EMB, QKVN);
  k_transpose_cvt<<<dim3(EMB / 32, EMB / 32), dim3(256), 0, stream>>>(out_w, outT, EMB, EMB);
  // 1D grids: bn fastest within bm (tiles sharing an A-panel are consecutive)
  k_gemm_bias<<<dim3((TOK / 128) * (QKVN / 128)), dim3(256), 0, stream>>>(x16, qkvT, qkv_b, qkvb, TOK, QKVN, EMB);
  k_attn<<<dim3(TOK), dim3(64), 0, stream>>>(qkvb, attno);
  k_gemm_bias<<<dim3((TOK / 128) * (EMB / 128)), dim3(256), 0, stream>>>(attno, outT, out_b, out2, TOK, EMB, EMB);
  k_cls<<<dim3(BATCH), dim3(256), 0, stream>>>(out2, cls_w, cls_b, logits);
}